// Round 12
// baseline (509.188 us; speedup 1.0000x reference)
//
#include <hip/hip_runtime.h>
#include <math.h>

// GNNLayer: 4-head GAT-like layer, MFMA edition.
//   feats[h] = relu(x @ W1[h] + b1[h]) @ W2[h] + b2[h]            [N,64]
//   score[e] = s1[src]+s2[dst]+aw_e*elem+ab ; w = exp(score)  (shift-invariant)
//   out[n, h*64+d] = sum_{e: src=n} w*f_dst[d] / sum w   (CSR pull, no atomics)
//
// R5: feats on MFMA. R7: aggregate unroll-8. R8: merged heads + bf16 feats +
//     edgemax deleted (total 500us).
// R11: feats was latency-bound (144us, MfmaUtil 9%, VALUBusy 10%, occ 16%):
//     67.6KB LDS -> 2 blocks/CU = 2 waves/SIMD; W1T B-gathers (~200cy L2) vs
//     80cy MFMA cover per kk -> stall each iter. Fix: 32-row tile -> 33.8KB
//     LDS -> 4 blocks/CU = 4 waves/SIMD, grid 782->1563, launch_bounds(256,4).
//     Layer2: wave owns 16-col strip; s1/s2 via [32][4] cross-wave LDS reduce.

#define N_HEADS 4
#define IN_DIM 256
#define HID_DIM 256
#define OUT_DIM 64
#define ATT_STRIDE (2 * OUT_DIM + 1) // 129
#define LDSP 264                     // padded bf16 row stride

typedef __attribute__((ext_vector_type(8))) short bf16x8;
typedef __attribute__((ext_vector_type(4))) float f32x4;

__device__ __forceinline__ unsigned short bf16rne(float f) {
  unsigned int u = __float_as_uint(f);
  u += 0x7fffu + ((u >> 16) & 1u);
  return (unsigned short)(u >> 16);
}

// ---------------- weight convert: W1T[h][j][k], W2T[h][d][k] in bf16 ----------------

#define W1N (N_HEADS * IN_DIM * HID_DIM)
#define W2N (N_HEADS * HID_DIM * OUT_DIM)

__global__ __launch_bounds__(256) void convw_kernel(const float* __restrict__ W1,
                                                    const float* __restrict__ W2,
                                                    unsigned short* __restrict__ W1T,
                                                    unsigned short* __restrict__ W2T) {
  int id = blockIdx.x * 256 + threadIdx.x;
  if (id < W1N) {
    int k = id & 255, j = (id >> 8) & 255, h = id >> 16;
    W1T[id] = bf16rne(W1[((size_t)h * 256 + k) * 256 + j]);
  } else if (id < W1N + W2N) {
    int t = id - W1N;
    int k = t & 255, d = (t >> 8) & 63, h = t >> 14;
    W2T[t] = bf16rne(W2[((size_t)h * 256 + k) * 64 + d]);
  }
}

// ---------------- CSR construction ----------------

__global__ __launch_bounds__(256) void count_kernel(const int* __restrict__ src,
                                                    int* __restrict__ cnt, int E) {
  int e = blockIdx.x * 256 + threadIdx.x;
  if (e < E) atomicAdd(&cnt[src[e]], 1);
}

__global__ __launch_bounds__(1024) void scan_kernel(const int* __restrict__ cnt,
                                                    int* __restrict__ offs, int N) {
  __shared__ int part[1024];
  int t = threadIdx.x;
  int chunk = (N + 1023) >> 10;
  int s0 = t * chunk;
  int s1e = min(s0 + chunk, N);
  int sum = 0;
  for (int i = s0; i < s1e; ++i) sum += cnt[i];
  part[t] = sum;
  __syncthreads();
  for (int off = 1; off < 1024; off <<= 1) {
    int v = (t >= off) ? part[t - off] : 0;
    __syncthreads();
    part[t] += v;
    __syncthreads();
  }
  int run = (t == 0) ? 0 : part[t - 1];
  for (int i = s0; i < s1e; ++i) { offs[i] = run; run += cnt[i]; }
  if (t == 0) offs[N] = part[1023];
}

// writes CSR-ordered dst/elem copies (no eid indirection in aggregate)
__global__ __launch_bounds__(256) void scatter_kernel(
    const int* __restrict__ src, const int* __restrict__ dst,
    const float* __restrict__ elem, const int* __restrict__ offs,
    int* __restrict__ cur, int* __restrict__ dst2, float* __restrict__ elem2,
    int E) {
  int e = blockIdx.x * 256 + threadIdx.x;
  if (e < E) {
    int s = src[e];
    int pos = offs[s] + atomicAdd(&cur[s], 1);
    dst2[pos] = dst[e];
    elem2[pos] = elem[e];
  }
}

// ---------------- fused MFMA MLP, all 4 heads, 32-row tile ----------------
// grid: ceil(N/32), block 256 = 4 waves, 4 blocks/CU (33.8 KB LDS).
// Layer1: 32x256; wave w owns 64-col strip (2x4 frags).
// Layer2: 32x64; wave w owns 16-col strip d=w*16+lr (2 frags).
// Fragment maps (verified m89/m92): A/B lane&15=m/n, k=8*(lane>>4)+j;
//                                   D col=lane&15, row=4*(lane>>4)+reg.

__global__ __launch_bounds__(256, 4) void feats_kernel(
    const float* __restrict__ x, const unsigned short* __restrict__ W1T,
    const float* __restrict__ b1, const unsigned short* __restrict__ W2T,
    const float* __restrict__ b2, const float* __restrict__ attn_w,
    const float* __restrict__ attn_b, unsigned short* __restrict__ feats_g,
    float* __restrict__ s1p, float* __restrict__ s2p, int N) {
  __shared__ __align__(16) unsigned short xs[32 * LDSP]; // 16.9 KB
  __shared__ __align__(16) unsigned short hs[32 * LDSP]; // 16.9 KB
  __shared__ float part1[32][4], part2[32][4];           // 1 KB

  int n0 = blockIdx.x * 32;
  int tid = threadIdx.x;
  int w = tid >> 6, l = tid & 63;
  int lr = l & 15, kb = l >> 4;

  // ---- stage x tile ONCE (f32 -> bf16 LDS), zero-fill rows >= N ----
#pragma unroll
  for (int i = 0; i < 4; ++i) {
    int flat = i * 2048 + tid * 8;
    int r = flat >> 8, c = flat & 255;
    int n = n0 + r;
    float4 v0 = make_float4(0.f, 0.f, 0.f, 0.f), v1 = v0;
    if (n < N) {
      const float* p = x + (size_t)n * IN_DIM + c;
      v0 = *(const float4*)p;
      v1 = *(const float4*)(p + 4);
    }
    uint4 pk;
    pk.x = (unsigned)bf16rne(v0.x) | ((unsigned)bf16rne(v0.y) << 16);
    pk.y = (unsigned)bf16rne(v0.z) | ((unsigned)bf16rne(v0.w) << 16);
    pk.z = (unsigned)bf16rne(v1.x) | ((unsigned)bf16rne(v1.y) << 16);
    pk.w = (unsigned)bf16rne(v1.z) | ((unsigned)bf16rne(v1.w) << 16);
    *(uint4*)&xs[r * LDSP + c] = pk;
  }
  __syncthreads();

  int j0 = w * 64;
  for (int h = 0; h < N_HEADS; ++h) {
    // ---- layer 1: wave col strip j0, rows 0..31 ----
    const unsigned short* W1Th = W1T + (size_t)h * 256 * 256;
    f32x4 acc[2][4];
#pragma unroll
    for (int mi = 0; mi < 2; ++mi)
#pragma unroll
      for (int ni = 0; ni < 4; ++ni) acc[mi][ni] = (f32x4){0.f, 0.f, 0.f, 0.f};

#pragma unroll
    for (int kk = 0; kk < 8; ++kk) {
      int k0 = kk * 32 + kb * 8;
      bf16x8 a[2], b[4];
#pragma unroll
      for (int mi = 0; mi < 2; ++mi)
        a[mi] = *(const bf16x8*)&xs[(mi * 16 + lr) * LDSP + k0];
#pragma unroll
      for (int ni = 0; ni < 4; ++ni)
        b[ni] = *(const bf16x8*)(W1Th + (size_t)(j0 + ni * 16 + lr) * 256 + k0);
#pragma unroll
      for (int mi = 0; mi < 2; ++mi)
#pragma unroll
        for (int ni = 0; ni < 4; ++ni)
          acc[mi][ni] = __builtin_amdgcn_mfma_f32_16x16x32_bf16(a[mi], b[ni],
                                                                acc[mi][ni], 0, 0, 0);
    }

    // ---- bias + relu -> hs ----
    float b1v[4];
#pragma unroll
    for (int ni = 0; ni < 4; ++ni) b1v[ni] = b1[h * HID_DIM + j0 + ni * 16 + lr];
    __syncthreads(); // prev head's layer-2 hs reads done
#pragma unroll
    for (int mi = 0; mi < 2; ++mi)
#pragma unroll
      for (int ni = 0; ni < 4; ++ni)
#pragma unroll
        for (int r = 0; r < 4; ++r) {
          float v = fmaxf(acc[mi][ni][r] + b1v[ni], 0.0f);
          hs[(mi * 16 + kb * 4 + r) * LDSP + (j0 + ni * 16 + lr)] = bf16rne(v);
        }
    __syncthreads();

    // ---- layer 2: wave col strip d = w*16+lr, rows 0..31 ----
    const unsigned short* W2Th = W2T + (size_t)h * 64 * 256;
    f32x4 acc2[2];
#pragma unroll
    for (int mi = 0; mi < 2; ++mi) acc2[mi] = (f32x4){0.f, 0.f, 0.f, 0.f};
#pragma unroll
    for (int kk = 0; kk < 8; ++kk) {
      int k0 = kk * 32 + kb * 8;
      bf16x8 bfr = *(const bf16x8*)(W2Th + (size_t)(w * 16 + lr) * 256 + k0);
#pragma unroll
      for (int mi = 0; mi < 2; ++mi) {
        bf16x8 a = *(const bf16x8*)&hs[(mi * 16 + lr) * LDSP + k0];
        acc2[mi] = __builtin_amdgcn_mfma_f32_16x16x32_bf16(a, bfr, acc2[mi], 0, 0, 0);
      }
    }

    // ---- epilogue: feats_g (bf16) + per-wave s1/s2 partials ----
    const float* awh = attn_w + h * ATT_STRIDE;
    int d = w * 16 + lr;
    float a1 = awh[d], a2c = awh[OUT_DIM + d], b2d = b2[h * OUT_DIM + d];
#pragma unroll
    for (int mi = 0; mi < 2; ++mi)
#pragma unroll
      for (int r = 0; r < 4; ++r) {
        float v = acc2[mi][r] + b2d;
        int row = mi * 16 + kb * 4 + r;
        int n = n0 + row;
        if (n < N) feats_g[((size_t)h * N + n) * OUT_DIM + d] = bf16rne(v);
        float p1 = v * a1, p2 = v * a2c;
#pragma unroll
        for (int m = 1; m < 16; m <<= 1) {
          p1 += __shfl_xor(p1, m, 64);
          p2 += __shfl_xor(p2, m, 64);
        }
        if (lr == 0) {
          part1[row][w] = p1;
          part2[row][w] = p2;
        }
      }
    __syncthreads();
    if (tid < 32) {
      int n = n0 + tid;
      if (n < N) {
        float q1 = part1[tid][0] + part1[tid][1] + part1[tid][2] + part1[tid][3];
        float q2 = part2[tid][0] + part2[tid][1] + part2[tid][2] + part2[tid][3];
        s1p[(size_t)n * N_HEADS + h] = q1;
        s2p[(size_t)n * N_HEADS + h] = q2;
      }
    }
  }
}

// ---------------- pull aggregation ----------------
// block = 4 waves (one per head) for node blockIdx.x.
// wave: lane half j=l>>5 processes edges of parity j; lane pair-dim dp=l&31
// covers dims {2dp, 2dp+1} via one dword (2 bf16) load per feats row.

#define AGG_U 8

__global__ __launch_bounds__(256) void aggregate_kernel(
    const int* __restrict__ dst2, const float* __restrict__ elem2,
    const int* __restrict__ offs, const float* __restrict__ s1p,
    const float* __restrict__ s2p, const unsigned short* __restrict__ feats_g,
    const float* __restrict__ attn_w, const float* __restrict__ attn_b,
    float* __restrict__ out, int N) {
  int n = blockIdx.x;
  int h = threadIdx.x >> 6;
  int l = threadIdx.x & 63;
  int j = l >> 5, dp = l & 31;
  int beg = offs[n], end = offs[n + 1];
  float base = s1p[(size_t)n * N_HEADS + h] + attn_b[h];
  float awe = attn_w[h * ATT_STRIDE + 2 * OUT_DIM];
  const unsigned short* fg = feats_g + (size_t)h * N * OUT_DIM;
  float acc0 = 0.f, acc1 = 0.f, rs = 0.f;

  for (int p = beg; p < end; p += 2 * AGG_U) {
    int dn[AGG_U];
    float el[AGG_U];
#pragma unroll
    for (int i = 0; i < AGG_U; ++i) {
      int q = p + 2 * i + j;
      int qq = (q < end) ? q : beg; // beg valid whenever loop body runs
      dn[i] = dst2[qq];
      el[i] = elem2[qq];
    }
    float s2v[AGG_U];
    unsigned int fv[AGG_U];
#pragma unroll
    for (int i = 0; i < AGG_U; ++i) s2v[i] = s2p[(size_t)dn[i] * N_HEADS + h];
#pragma unroll
    for (int i = 0; i < AGG_U; ++i)
      fv[i] = *(const unsigned int*)&fg[(size_t)dn[i] * OUT_DIM + 2 * dp];
#pragma unroll
    for (int i = 0; i < AGG_U; ++i) {
      float wv = (p + 2 * i + j < end) ? __expf(base + s2v[i] + awe * el[i]) : 0.f;
      float f0 = __uint_as_float(fv[i] << 16);
      float f1 = __uint_as_float(fv[i] & 0xffff0000u);
      acc0 = fmaf(wv, f0, acc0);
      acc1 = fmaf(wv, f1, acc1);
      rs += wv;
    }
  }
  // combine the two edge-parity halves (lane l <-> l^32)
  acc0 += __shfl_xor(acc0, 32, 64);
  acc1 += __shfl_xor(acc1, 32, 64);
  rs += __shfl_xor(rs, 32, 64);
  if (j == 0) {
    float inv = 1.0f / rs;
    float2 o = make_float2(acc0 * inv, acc1 * inv);
    *(float2*)&out[(size_t)n * (N_HEADS * OUT_DIM) + h * OUT_DIM + 2 * dp] = o;
  }
}

// ---------------- launch ----------------

extern "C" void kernel_launch(void* const* d_in, const int* in_sizes, int n_in,
                              void* d_out, int out_size, void* d_ws, size_t ws_size,
                              hipStream_t stream) {
  const float* x = (const float*)d_in[0];
  const int* idx = (const int*)d_in[1];
  const float* elem = (const float*)d_in[2];
  const float* W1 = (const float*)d_in[3];
  const float* b1 = (const float*)d_in[4];
  const float* W2 = (const float*)d_in[5];
  const float* b2 = (const float*)d_in[6];
  const float* attn_w = (const float*)d_in[7];
  const float* attn_b = (const float*)d_in[8];
  float* out = (float*)d_out;

  int N = in_sizes[0] / IN_DIM; // 50000
  int E = in_sizes[2];          // 800000
  const int* src = idx;
  const int* dst = idx + E;
  int nb = (E + 255) / 256;

  // workspace layout (~35 MB)
  unsigned short* W1T = (unsigned short*)d_ws;                  // 262144 bf16
  unsigned short* W2T = W1T + W1N;                              // 65536 bf16
  unsigned short* feats_g = W2T + W2N;                          // H*N*64 bf16
  float* s1p = (float*)(feats_g + (size_t)N_HEADS * N * OUT_DIM); // N*4
  float* s2p = s1p + (size_t)N * N_HEADS;                       // N*4
  int* offs = (int*)(s2p + (size_t)N * N_HEADS);                // N+1 (padded)
  int* cur = offs + (N + 64);                                   // N (padded)
  int* dst2 = cur + (N + 64);                                   // E
  float* elem2 = (float*)(dst2 + E);                            // E

  convw_kernel<<<(W1N + W2N + 255) / 256, 256, 0, stream>>>(W1, W2, W1T, W2T);

  hipMemsetAsync(cur, 0, sizeof(int) * (size_t)N, stream);
  count_kernel<<<nb, 256, 0, stream>>>(src, cur, E);
  scan_kernel<<<1, 1024, 0, stream>>>(cur, offs, N);
  hipMemsetAsync(cur, 0, sizeof(int) * (size_t)N, stream);
  scatter_kernel<<<nb, 256, 0, stream>>>(src, dst, elem, offs, cur, dst2, elem2, E);

  feats_kernel<<<(N + 31) / 32, 256, 0, stream>>>(x, W1T, b1, W2T, b2, attn_w,
                                                  attn_b, feats_g, s1p, s2p, N);
  aggregate_kernel<<<N, 256, 0, stream>>>(dst2, elem2, offs, s1p, s2p, feats_g,
                                          attn_w, attn_b, out, N);
}

// Round 13
// 453.022 us; speedup vs baseline: 1.1240x; 1.1240x over previous
//
#include <hip/hip_runtime.h>
#include <math.h>

// GNNLayer: 4-head GAT-like layer, MFMA edition.
//   feats[h] = relu(x @ W1[h] + b1[h]) @ W2[h] + b2[h]            [N,64]
//   score[e] = s1[src]+s2[dst]+aw_e*elem+ab ; w = exp(score)  (shift-invariant)
//   out[n, h*64+d] = sum_{e: src=n} w*f_dst[d] / sum w   (CSR pull, no atomics)
//
// R11/R12 lesson: feats time was invariant to occupancy (144us@2blk/CU vs
// 161us@4blk/CU, all pipes <10%) -> per-block W1T re-gather latency (not
// pipelined at VGPR=52) was the invariant cost.
// R12->13: WEIGHT-STATIONARY feats. Block owns one head; each wave preloads
// its 64-col W1 strip into registers ONCE (32 x bf16x8 = 128 VGPR, static
// indexing) and grid-strides over ~12 node tiles. Inner loop: stage x ->
// MFMA from registers. Grid 4 heads x 128 stripes; head-blocks of a stripe
// adjacent -> x tile L3-reused across heads.

#define N_HEADS 4
#define IN_DIM 256
#define HID_DIM 256
#define OUT_DIM 64
#define ATT_STRIDE (2 * OUT_DIM + 1) // 129
#define LDSP 264                     // padded bf16 row stride
#define NSTRIPE 128                  // node-stripes; grid = 4*NSTRIPE

typedef __attribute__((ext_vector_type(8))) short bf16x8;
typedef __attribute__((ext_vector_type(4))) float f32x4;

__device__ __forceinline__ unsigned short bf16rne(float f) {
  unsigned int u = __float_as_uint(f);
  u += 0x7fffu + ((u >> 16) & 1u);
  return (unsigned short)(u >> 16);
}

// ---------------- weight convert: W1T[h][j][k], W2T[h][d][k] in bf16 ----------------

#define W1N (N_HEADS * IN_DIM * HID_DIM)
#define W2N (N_HEADS * HID_DIM * OUT_DIM)

__global__ __launch_bounds__(256) void convw_kernel(const float* __restrict__ W1,
                                                    const float* __restrict__ W2,
                                                    unsigned short* __restrict__ W1T,
                                                    unsigned short* __restrict__ W2T) {
  int id = blockIdx.x * 256 + threadIdx.x;
  if (id < W1N) {
    int k = id & 255, j = (id >> 8) & 255, h = id >> 16;
    W1T[id] = bf16rne(W1[((size_t)h * 256 + k) * 256 + j]);
  } else if (id < W1N + W2N) {
    int t = id - W1N;
    int k = t & 255, d = (t >> 8) & 63, h = t >> 14;
    W2T[t] = bf16rne(W2[((size_t)h * 256 + k) * 64 + d]);
  }
}

// ---------------- CSR construction ----------------

__global__ __launch_bounds__(256) void count_kernel(const int* __restrict__ src,
                                                    int* __restrict__ cnt, int E) {
  int e = blockIdx.x * 256 + threadIdx.x;
  if (e < E) atomicAdd(&cnt[src[e]], 1);
}

__global__ __launch_bounds__(1024) void scan_kernel(const int* __restrict__ cnt,
                                                    int* __restrict__ offs, int N) {
  __shared__ int part[1024];
  int t = threadIdx.x;
  int chunk = (N + 1023) >> 10;
  int s0 = t * chunk;
  int s1e = min(s0 + chunk, N);
  int sum = 0;
  for (int i = s0; i < s1e; ++i) sum += cnt[i];
  part[t] = sum;
  __syncthreads();
  for (int off = 1; off < 1024; off <<= 1) {
    int v = (t >= off) ? part[t - off] : 0;
    __syncthreads();
    part[t] += v;
    __syncthreads();
  }
  int run = (t == 0) ? 0 : part[t - 1];
  for (int i = s0; i < s1e; ++i) { offs[i] = run; run += cnt[i]; }
  if (t == 0) offs[N] = part[1023];
}

// writes CSR-ordered dst/elem copies (no eid indirection in aggregate)
__global__ __launch_bounds__(256) void scatter_kernel(
    const int* __restrict__ src, const int* __restrict__ dst,
    const float* __restrict__ elem, const int* __restrict__ offs,
    int* __restrict__ cur, int* __restrict__ dst2, float* __restrict__ elem2,
    int E) {
  int e = blockIdx.x * 256 + threadIdx.x;
  if (e < E) {
    int s = src[e];
    int pos = offs[s] + atomicAdd(&cur[s], 1);
    dst2[pos] = dst[e];
    elem2[pos] = elem[e];
  }
}

// ---------------- weight-stationary fused MFMA MLP ----------------
// grid: 4*NSTRIPE blocks; block = 256 thr = 4 waves; head = blockIdx.x & 3.
// Wave w holds W1[h] cols [w*64, w*64+64) as 32 register B-frags; loops over
// node tiles t = stripe, stripe+NSTRIPE, ...
// Fragment maps (verified m89/m92): A/B lane&15=m/n, k=8*(lane>>4)+j;
//                                   D col=lane&15, row=4*(lane>>4)+reg.

__global__ __launch_bounds__(256, 2) void feats_kernel(
    const float* __restrict__ x, const unsigned short* __restrict__ W1T,
    const float* __restrict__ b1, const unsigned short* __restrict__ W2T,
    const float* __restrict__ b2, const float* __restrict__ attn_w,
    const float* __restrict__ attn_b, unsigned short* __restrict__ feats_g,
    float* __restrict__ s1p, float* __restrict__ s2p, int N) {
  __shared__ __align__(16) unsigned short xs[32 * LDSP]; // 16.9 KB
  __shared__ __align__(16) unsigned short hs[32 * LDSP]; // 16.9 KB
  __shared__ float part1[32][4], part2[32][4];           // 1 KB

  int tid = threadIdx.x;
  int w = tid >> 6, l = tid & 63;
  int lr = l & 15, kb = l >> 4;
  int h = blockIdx.x & 3;
  int stripe = blockIdx.x >> 2;
  int j0 = w * 64;

  // ---- preload W1 strip into registers (once per block) ----
  const unsigned short* W1Th = W1T + (size_t)h * 256 * 256;
  const unsigned short* W2Th = W2T + (size_t)h * 64 * 256;
  bf16x8 w1b[8][4];
#pragma unroll
  for (int kk = 0; kk < 8; ++kk)
#pragma unroll
    for (int ni = 0; ni < 4; ++ni)
      w1b[kk][ni] =
          *(const bf16x8*)(W1Th + (size_t)(j0 + ni * 16 + lr) * 256 + kk * 32 + kb * 8);

  float b1v[4];
#pragma unroll
  for (int ni = 0; ni < 4; ++ni) b1v[ni] = b1[h * HID_DIM + j0 + ni * 16 + lr];
  int d = w * 16 + lr;
  const float* awh = attn_w + h * ATT_STRIDE;
  float a1 = awh[d], a2c = awh[OUT_DIM + d], b2d = b2[h * OUT_DIM + d];

  int ntiles = (N + 31) >> 5;
  for (int t = stripe; t < ntiles; t += NSTRIPE) {
    int n0 = t * 32;

    // ---- stage x tile (f32 -> bf16 LDS), zero-fill rows >= N ----
#pragma unroll
    for (int i = 0; i < 4; ++i) {
      int flat = i * 2048 + tid * 8;
      int r = flat >> 8, c = flat & 255;
      int n = n0 + r;
      float4 v0 = make_float4(0.f, 0.f, 0.f, 0.f), v1 = v0;
      if (n < N) {
        const float* p = x + (size_t)n * IN_DIM + c;
        v0 = *(const float4*)p;
        v1 = *(const float4*)(p + 4);
      }
      uint4 pk;
      pk.x = (unsigned)bf16rne(v0.x) | ((unsigned)bf16rne(v0.y) << 16);
      pk.y = (unsigned)bf16rne(v0.z) | ((unsigned)bf16rne(v0.w) << 16);
      pk.z = (unsigned)bf16rne(v1.x) | ((unsigned)bf16rne(v1.y) << 16);
      pk.w = (unsigned)bf16rne(v1.z) | ((unsigned)bf16rne(v1.w) << 16);
      *(uint4*)&xs[r * LDSP + c] = pk;
    }
    __syncthreads(); // xs staged (also: prev tile fully done -> safe overwrite)

    // ---- layer 1: B from registers ----
    f32x4 acc[2][4];
#pragma unroll
    for (int mi = 0; mi < 2; ++mi)
#pragma unroll
      for (int ni = 0; ni < 4; ++ni) acc[mi][ni] = (f32x4){0.f, 0.f, 0.f, 0.f};
#pragma unroll
    for (int kk = 0; kk < 8; ++kk) {
      int k0 = kk * 32 + kb * 8;
      bf16x8 a0 = *(const bf16x8*)&xs[lr * LDSP + k0];
      bf16x8 a1f = *(const bf16x8*)&xs[(16 + lr) * LDSP + k0];
#pragma unroll
      for (int ni = 0; ni < 4; ++ni) {
        acc[0][ni] = __builtin_amdgcn_mfma_f32_16x16x32_bf16(a0, w1b[kk][ni],
                                                             acc[0][ni], 0, 0, 0);
        acc[1][ni] = __builtin_amdgcn_mfma_f32_16x16x32_bf16(a1f, w1b[kk][ni],
                                                             acc[1][ni], 0, 0, 0);
      }
    }

    // ---- bias + relu -> hs (xs readers done within this wave; cross-wave
    //      hs readers of PREV tile finished before this tile's first sync) ----
#pragma unroll
    for (int mi = 0; mi < 2; ++mi)
#pragma unroll
      for (int ni = 0; ni < 4; ++ni)
#pragma unroll
        for (int r = 0; r < 4; ++r) {
          float v = fmaxf(acc[mi][ni][r] + b1v[ni], 0.0f);
          hs[(mi * 16 + kb * 4 + r) * LDSP + (j0 + ni * 16 + lr)] = bf16rne(v);
        }
    __syncthreads(); // hs complete

    // ---- layer 2: wave col strip d = w*16+lr ----
    f32x4 acc2[2];
#pragma unroll
    for (int mi = 0; mi < 2; ++mi) acc2[mi] = (f32x4){0.f, 0.f, 0.f, 0.f};
#pragma unroll
    for (int kk = 0; kk < 8; ++kk) {
      int k0 = kk * 32 + kb * 8;
      bf16x8 bfr = *(const bf16x8*)(W2Th + (size_t)(w * 16 + lr) * 256 + k0);
#pragma unroll
      for (int mi = 0; mi < 2; ++mi) {
        bf16x8 a = *(const bf16x8*)&hs[(mi * 16 + lr) * LDSP + k0];
        acc2[mi] = __builtin_amdgcn_mfma_f32_16x16x32_bf16(a, bfr, acc2[mi], 0, 0, 0);
      }
    }

    // ---- epilogue: feats_g (bf16) + per-wave s1/s2 partials ----
#pragma unroll
    for (int mi = 0; mi < 2; ++mi)
#pragma unroll
      for (int r = 0; r < 4; ++r) {
        float v = acc2[mi][r] + b2d;
        int row = mi * 16 + kb * 4 + r;
        int n = n0 + row;
        if (n < N) feats_g[((size_t)h * N + n) * OUT_DIM + d] = bf16rne(v);
        float p1 = v * a1, p2 = v * a2c;
#pragma unroll
        for (int m = 1; m < 16; m <<= 1) {
          p1 += __shfl_xor(p1, m, 64);
          p2 += __shfl_xor(p2, m, 64);
        }
        if (lr == 0) {
          part1[row][w] = p1;
          part2[row][w] = p2;
        }
      }
    __syncthreads(); // part arrays complete
    if (tid < 32) {
      int n = n0 + tid;
      if (n < N) {
        float q1 = part1[tid][0] + part1[tid][1] + part1[tid][2] + part1[tid][3];
        float q2 = part2[tid][0] + part2[tid][1] + part2[tid][2] + part2[tid][3];
        s1p[(size_t)n * N_HEADS + h] = q1;
        s2p[(size_t)n * N_HEADS + h] = q2;
      }
    }
    // next-iter staging ordered vs part readers by the first sync of next tile
  }
}

// ---------------- pull aggregation ----------------
// block = 4 waves (one per head) for node blockIdx.x.
// wave: lane half j=l>>5 processes edges of parity j; lane pair-dim dp=l&31
// covers dims {2dp, 2dp+1} via one dword (2 bf16) load per feats row.

#define AGG_U 8

__global__ __launch_bounds__(256) void aggregate_kernel(
    const int* __restrict__ dst2, const float* __restrict__ elem2,
    const int* __restrict__ offs, const float* __restrict__ s1p,
    const float* __restrict__ s2p, const unsigned short* __restrict__ feats_g,
    const float* __restrict__ attn_w, const float* __restrict__ attn_b,
    float* __restrict__ out, int N) {
  int n = blockIdx.x;
  int h = threadIdx.x >> 6;
  int l = threadIdx.x & 63;
  int j = l >> 5, dp = l & 31;
  int beg = offs[n], end = offs[n + 1];
  float base = s1p[(size_t)n * N_HEADS + h] + attn_b[h];
  float awe = attn_w[h * ATT_STRIDE + 2 * OUT_DIM];
  const unsigned short* fg = feats_g + (size_t)h * N * OUT_DIM;
  float acc0 = 0.f, acc1 = 0.f, rs = 0.f;

  for (int p = beg; p < end; p += 2 * AGG_U) {
    int dn[AGG_U];
    float el[AGG_U];
#pragma unroll
    for (int i = 0; i < AGG_U; ++i) {
      int q = p + 2 * i + j;
      int qq = (q < end) ? q : beg; // beg valid whenever loop body runs
      dn[i] = dst2[qq];
      el[i] = elem2[qq];
    }
    float s2v[AGG_U];
    unsigned int fv[AGG_U];
#pragma unroll
    for (int i = 0; i < AGG_U; ++i) s2v[i] = s2p[(size_t)dn[i] * N_HEADS + h];
#pragma unroll
    for (int i = 0; i < AGG_U; ++i)
      fv[i] = *(const unsigned int*)&fg[(size_t)dn[i] * OUT_DIM + 2 * dp];
#pragma unroll
    for (int i = 0; i < AGG_U; ++i) {
      float wv = (p + 2 * i + j < end) ? __expf(base + s2v[i] + awe * el[i]) : 0.f;
      float f0 = __uint_as_float(fv[i] << 16);
      float f1 = __uint_as_float(fv[i] & 0xffff0000u);
      acc0 = fmaf(wv, f0, acc0);
      acc1 = fmaf(wv, f1, acc1);
      rs += wv;
    }
  }
  // combine the two edge-parity halves (lane l <-> l^32)
  acc0 += __shfl_xor(acc0, 32, 64);
  acc1 += __shfl_xor(acc1, 32, 64);
  rs += __shfl_xor(rs, 32, 64);
  if (j == 0) {
    float inv = 1.0f / rs;
    float2 o = make_float2(acc0 * inv, acc1 * inv);
    *(float2*)&out[(size_t)n * (N_HEADS * OUT_DIM) + h * OUT_DIM + 2 * dp] = o;
  }
}

// ---------------- launch ----------------

extern "C" void kernel_launch(void* const* d_in, const int* in_sizes, int n_in,
                              void* d_out, int out_size, void* d_ws, size_t ws_size,
                              hipStream_t stream) {
  const float* x = (const float*)d_in[0];
  const int* idx = (const int*)d_in[1];
  const float* elem = (const float*)d_in[2];
  const float* W1 = (const float*)d_in[3];
  const float* b1 = (const float*)d_in[4];
  const float* W2 = (const float*)d_in[5];
  const float* b2 = (const float*)d_in[6];
  const float* attn_w = (const float*)d_in[7];
  const float* attn_b = (const float*)d_in[8];
  float* out = (float*)d_out;

  int N = in_sizes[0] / IN_DIM; // 50000
  int E = in_sizes[2];          // 800000
  const int* src = idx;
  const int* dst = idx + E;
  int nb = (E + 255) / 256;

  // workspace layout (~35 MB)
  unsigned short* W1T = (unsigned short*)d_ws;                  // 262144 bf16
  unsigned short* W2T = W1T + W1N;                              // 65536 bf16
  unsigned short* feats_g = W2T + W2N;                          // H*N*64 bf16
  float* s1p = (float*)(feats_g + (size_t)N_HEADS * N * OUT_DIM); // N*4
  float* s2p = s1p + (size_t)N * N_HEADS;                       // N*4
  int* offs = (int*)(s2p + (size_t)N * N_HEADS);                // N+1 (padded)
  int* cur = offs + (N + 64);                                   // N (padded)
  int* dst2 = cur + (N + 64);                                   // E
  float* elem2 = (float*)(dst2 + E);                            // E

  convw_kernel<<<(W1N + W2N + 255) / 256, 256, 0, stream>>>(W1, W2, W1T, W2T);

  hipMemsetAsync(cur, 0, sizeof(int) * (size_t)N, stream);
  count_kernel<<<nb, 256, 0, stream>>>(src, cur, E);
  scan_kernel<<<1, 1024, 0, stream>>>(cur, offs, N);
  hipMemsetAsync(cur, 0, sizeof(int) * (size_t)N, stream);
  scatter_kernel<<<nb, 256, 0, stream>>>(src, dst, elem, offs, cur, dst2, elem2, E);

  feats_kernel<<<4 * NSTRIPE, 256, 0, stream>>>(x, W1T, b1, W2T, b2, attn_w,
                                                attn_b, feats_g, s1p, s2p, N);
  aggregate_kernel<<<N, 256, 0, stream>>>(dst2, elem2, offs, s1p, s2p, feats_g,
                                          attn_w, attn_b, out, N);
}